// Round 17
// baseline (618.082 us; speedup 1.0000x reference)
//
#include <hip/hip_runtime.h>
#include <hip/hip_bf16.h>
#include <hip/hip_fp16.h>
#include <math.h>

#define NN 25000
#define EE 400000
#define BB 64
#define FF 32
#define EDD 8
#define HH 4
#define CC 32
#define HCC 128
#define LL 4
#define LINN 128

#define RSQRT_C 0.17677669529663687f  // 1/sqrt(32)
#define NREP 16                        // bnpart replicas
#define NREPP 8                        // pool replicas
// lstats region layout: bnpart[NREP*64] | gmax[NREPP*BB*32] (uint) | gsum[NREPP*BB*32]
#define GMAX_OFF (NREP * 64)
#define GSUM_OFF (NREP * 64 + NREPP * BB * 32)
#define LSTATS_WORDS (NREP * 64 + 2 * NREPP * BB * 32)

// ---------------- CSR build ----------------

__global__ void deg_kernel(const int* __restrict__ dst, int* __restrict__ deg) {
    int i = blockIdx.x * blockDim.x + threadIdx.x;
    if (i < EE) atomicAdd(&deg[dst[i]], 1);
}

// inclusive scan within 256-blocks; writes to rowp[i+1], block totals to blks.
// Also: degree histogram (for load-balance sort).
__global__ void scan1_kernel(const int* __restrict__ deg, int* __restrict__ rowp,
                             int* __restrict__ blks, int* __restrict__ hist) {
    __shared__ int s[256];
    int i = blockIdx.x * 256 + threadIdx.x;
    int v = (i < NN) ? deg[i] : 0;
    s[threadIdx.x] = v;
    if (i < NN) atomicAdd(&hist[v < 255 ? v : 255], 1);
    __syncthreads();
    for (int off = 1; off < 256; off <<= 1) {
        int t = (threadIdx.x >= off) ? s[threadIdx.x - off] : 0;
        __syncthreads();
        s[threadIdx.x] += t;
        __syncthreads();
    }
    if (i < NN) rowp[i + 1] = s[threadIdx.x];
    if (threadIdx.x == 255) blks[blockIdx.x] = s[255];
    if (i == 0) rowp[0] = 0;
}

// parallel exclusive scan of block totals (nb <= 128) + gstart binary searches  (r14-proven)
__global__ void scan2_kernel(int* __restrict__ blks, int nb,
                             const int* __restrict__ bidx, int* __restrict__ gstart) {
    __shared__ int s[128];
    int t = threadIdx.x;
    int v = (t < nb) ? blks[t] : 0;
    s[t] = v;
    __syncthreads();
    for (int off = 1; off < 128; off <<= 1) {
        int u = (t >= off) ? s[t - off] : 0;
        __syncthreads();
        s[t] += u;
        __syncthreads();
    }
    if (t < nb) blks[t] = s[t] - v;  // exclusive
    if (t <= BB) {
        int lo = 0, hi = NN;
        while (lo < hi) { int mid = (lo + hi) >> 1; if (bidx[mid] < t) lo = mid + 1; else hi = mid; }
        gstart[t] = lo;
    }
}

// descending-degree bin starts: binstart[d] = #nodes with degree > d
__global__ void binprep_kernel(const int* __restrict__ hist, int* __restrict__ binstart) {
    __shared__ int sb[256];
    int t = threadIdx.x;
    sb[t] = hist[t];
    __syncthreads();
    for (int off = 1; off < 256; off <<= 1) {
        int u = (t + off < 256) ? sb[t + off] : 0;
        __syncthreads();
        sb[t] += u;
        __syncthreads();
    }
    binstart[t] = sb[t] - hist[t];
}

// rowp finalize + load-balance scatter: perm slot by descending degree
__global__ void scan3_kernel(int* __restrict__ rowp, const int* __restrict__ blks,
                             const int* __restrict__ deg, const int* __restrict__ binstart,
                             int* __restrict__ bincnt, int* __restrict__ perm) {
    int i = blockIdx.x * 256 + threadIdx.x;
    if (i < NN) {
        rowp[i + 1] += blks[blockIdx.x];
        int d = deg[i]; d = (d < 255) ? d : 255;
        int pos = binstart[d] + atomicAdd(&bincnt[d], 1);
        perm[pos] = i;
    }
}

__global__ void fill_kernel(const int* __restrict__ dst, const int* __restrict__ rowp,
                            int* __restrict__ cnt2, int* __restrict__ eid) {
    int i = blockIdx.x * blockDim.x + threadIdx.x;
    if (i < EE) {
        int d = dst[i];
        int pos = rowp[d] + atomicAdd(&cnt2[d], 1);
        eid[pos] = i;
    }
}

// deterministic order: insertion-sort each node's edge list by edge id (scratch buffer)
__global__ void sortseg_kernel(const int* __restrict__ rowp, int* __restrict__ eid) {
    int n = blockIdx.x * 256 + threadIdx.x;
    if (n >= NN) return;
    int b = rowp[n], e = rowp[n + 1];
    int d = e - b;
    if (d <= 1) return;
    if (d <= 64) {
        int buf[64];
        for (int i = 0; i < d; ++i) buf[i] = eid[b + i];
        for (int i = 1; i < d; ++i) {
            int key = buf[i];
            int j = i - 1;
            while (j >= 0 && buf[j] > key) { buf[j + 1] = buf[j]; --j; }
            buf[j + 1] = key;
        }
        for (int i = 0; i < d; ++i) eid[b + i] = buf[i];
    } else {
        for (int i = b + 1; i < e; ++i) {
            int key = eid[i];
            int j = i - 1;
            while (j >= b && eid[j] > key) { eid[j + 1] = eid[j]; --j; }
            eid[j + 1] = key;
        }
    }
}

// gather src + edge-attr (fp16-packed) into CSR order (once per call, reused 4 layers)
__global__ void csr_gather_kernel(const int* __restrict__ csre, const int* __restrict__ srcA,
                                  const float* __restrict__ eattr,
                                  int* __restrict__ csrsrc, uint4* __restrict__ eh) {
    int j = blockIdx.x * blockDim.x + threadIdx.x;
    if (j < EE) {
        int e = csre[j];
        csrsrc[j] = srcA[e];
        const float4* s = (const float4*)(eattr + (size_t)e * 8);
        float4 s0 = s[0], s1 = s[1];
        __half2 h0 = __float22half2_rn(make_float2(s0.x, s0.y));
        __half2 h1 = __float22half2_rn(make_float2(s0.z, s0.w));
        __half2 h2 = __float22half2_rn(make_float2(s1.x, s1.y));
        __half2 h3 = __float22half2_rn(make_float2(s1.z, s1.w));
        uint4 o;
        o.x = *(unsigned*)&h0; o.y = *(unsigned*)&h1;
        o.z = *(unsigned*)&h2; o.w = *(unsigned*)&h3;
        eh[j] = o;
    }
}

// ---------------- per-layer: q,k,v,skip projections (+inline BN of input) ----------------
__global__ __launch_bounds__(256) void qkvs_kernel(
    const float* __restrict__ hin, int applyBN,
    const float* __restrict__ lstats_prev, float* __restrict__ lstats_cur,
    const float* __restrict__ gamma, const float* __restrict__ bnbeta,
    const float* __restrict__ Wq, const float* __restrict__ bq,
    const float* __restrict__ Wk, const float* __restrict__ bk,
    const float* __restrict__ Wv, const float* __restrict__ bv,
    const float* __restrict__ Ws, const float* __restrict__ bs,
    __half2* __restrict__ qo, __half2* __restrict__ kvo,
    __half2* __restrict__ so)
{
    if (blockIdx.x == 0) {
        for (int i = threadIdx.x; i < LSTATS_WORDS; i += 256) lstats_cur[i] = 0.0f;
    }
    __shared__ float xs[32][32];
    __shared__ float sbns[64];
    if (threadIdx.x < 32) {
        float scale = 1.0f, shift = 0.0f;
        if (applyBN) {
            float sm = 0.0f, sq = 0.0f;
#pragma unroll
            for (int r = 0; r < NREP; ++r) {
                sm += lstats_prev[r * 64 + threadIdx.x];
                sq += lstats_prev[r * 64 + 32 + threadIdx.x];
            }
            float mean = sm * (1.0f / NN);
            float var = sq * (1.0f / NN) - mean * mean;
            scale = gamma[threadIdx.x] * rsqrtf(var + 1e-5f);
            shift = bnbeta[threadIdx.x] - mean * scale;
        }
        sbns[threadIdx.x] = scale;
        sbns[32 + threadIdx.x] = shift;
    }
    int lane = threadIdx.x & 63;
    int sel = threadIdx.x >> 6;
    const float* W = (sel == 0) ? Wq : (sel == 1) ? Wk : (sel == 2) ? Wv : Ws;
    const float* bias = (sel == 0) ? bq : (sel == 1) ? bk : (sel == 2) ? bv : bs;
    float w0[32], w1[32];
#pragma unroll
    for (int f = 0; f < 32; ++f) {
        float2 t = *(const float2*)&W[f * 128 + 2 * lane];
        w0[f] = t.x; w1[f] = t.y;
    }
    float2 bvv = *(const float2*)&bias[2 * lane];

    int c = lane >> 1;
    int pr = lane & 1;
    int h2k = c * 4 + pr;          // __half2 slot for k within kv row
    int h2v = c * 4 + 2 + pr;      // __half2 slot for v within kv row

    for (int chunk = blockIdx.x * 32; chunk < NN; chunk += gridDim.x * 32) {
        __syncthreads();
        for (int i = threadIdx.x; i < 1024; i += 256) {
            int nn = chunk + (i >> 5);
            int ch = i & 31;
            float v = (nn < NN) ? hin[nn * 32 + ch] : 0.0f;
            xs[i >> 5][ch] = v * sbns[ch] + sbns[32 + ch];
        }
        __syncthreads();
        int nmax = NN - chunk; if (nmax > 32) nmax = 32;
        for (int nl = 0; nl < nmax; ++nl) {
            float a0 = bvv.x, a1 = bvv.y;
#pragma unroll
            for (int f4 = 0; f4 < 8; ++f4) {
                float4 xv = *(const float4*)&xs[nl][f4 * 4];
                a0 = fmaf(xv.x, w0[f4 * 4],     a0);
                a1 = fmaf(xv.x, w1[f4 * 4],     a1);
                a0 = fmaf(xv.y, w0[f4 * 4 + 1], a0);
                a1 = fmaf(xv.y, w1[f4 * 4 + 1], a1);
                a0 = fmaf(xv.z, w0[f4 * 4 + 2], a0);
                a1 = fmaf(xv.z, w1[f4 * 4 + 2], a1);
                a0 = fmaf(xv.w, w0[f4 * 4 + 3], a0);
                a1 = fmaf(xv.w, w1[f4 * 4 + 3], a1);
            }
            size_t node = (size_t)(chunk + nl);
            __half2 hv = __float22half2_rn(make_float2(a0, a1));
            if (sel == 0)      qo[node * 64 + lane] = hv;
            else if (sel == 1) kvo[node * 128 + h2k] = hv;
            else if (sel == 2) kvo[node * 128 + h2v] = hv;
            else               so[node * 64 + lane] = hv;
        }
    }
}

__device__ __forceinline__ unsigned fmap_u(float x) {
    unsigned u = __float_as_uint(x);
    return (u & 0x80000000u) ? ~u : (u | 0x80000000u);
}
__device__ __forceinline__ float funmap_u(unsigned u) {
    unsigned b = (u & 0x80000000u) ? (u & 0x7fffffffu) : ~u;
    return __uint_as_float(b);
}

// ---------------- fused attention + beta gate + Wlin + ELU + BN partials + pool partials ----------------
// 4 waves/block, 1 dst node per wave via perm (degree-sorted desc -> balanced blocks + LPT order).
// Lane c=lane&31 owns channels 4c..4c+3; half h=lane>>5 processes edge j = jb + h.
// NOTE: no min-waves launch bound — r13 showed forcing 8 waves/EU spills (VGPR 32, 8x traffic).
__global__ __launch_bounds__(256) void attn_kernel(
    const uint2* __restrict__ qh, const uint4* __restrict__ kvb4,
    const uint2* __restrict__ skh,
    const uint4* __restrict__ eh,         // fp16 edge attrs, 16B/edge
    const int* __restrict__ srcArr,       // csrsrc[j]
    const int* __restrict__ rowp,
    const int* __restrict__ bidx,
    const int* __restrict__ perm,
    const float* __restrict__ WeL, const float* __restrict__ beL,
    const float* __restrict__ WbL,
    const float* __restrict__ WlinL, const float* __restrict__ blinL,
    float* __restrict__ hlin, float* __restrict__ lstats,
    int doPool, int doWriteH)
{
    __shared__ __align__(16) float shc[4 * 128];
    __shared__ float sbn[64];
    __shared__ int snode[4];

    int tid = threadIdx.x;
    if (tid < 64) sbn[tid] = 0.0f;
    if (tid < 4) snode[tid] = perm[blockIdx.x * 4 + tid];
    __syncthreads();

    int w = tid >> 6;
    int lane = tid & 63;
    int n = snode[w];                     // NN = 6250*4: always valid

    {
        int c = lane & 31;
        int h = lane >> 5;

        // per-lane We rows for channels 4c..4c+3
        float4 we[8];
#pragma unroll
        for (int d = 0; d < 8; ++d) we[d] = *(const float4*)&WeL[d * 128 + 4 * c];
        float4 be4 = *(const float4*)&beL[4 * c];

        uint2 qraw = qh[(size_t)n * 32 + c];
        float2 q01 = __half22float2(*(const __half2*)&qraw.x);
        float2 q23 = __half22float2(*(const __half2*)&qraw.y);
        float4 q4 = make_float4(q01.x * RSQRT_C, q01.y * RSQRT_C,
                                q23.x * RSQRT_C, q23.y * RSQRT_C);

        int beg = rowp[n], end = rowp[n + 1];
        int cnt = end - beg;
        int last = end - 1;

        float s = 0.0f, a0 = 0.0f, a1 = 0.0f, a2 = 0.0f, a3 = 0.0f;

        // pipeline state (per half): edges j, j+2 in regs; src for j+4, j+6
        uint4 kvA = make_uint4(0u, 0u, 0u, 0u), kvB = kvA;
        uint4 eaA = kvA, eaB = kvA;
        int snC = 0, snD = 0;

        if (cnt > 0) {
            int j0 = beg + h;     j0 = (j0 < end) ? j0 : last;
            int j1 = beg + 2 + h; j1 = (j1 < end) ? j1 : last;
            int j2 = beg + 4 + h; j2 = (j2 < end) ? j2 : last;
            int j3 = beg + 6 + h; j3 = (j3 < end) ? j3 : last;
            int snA = srcArr[j0];
            int snB = srcArr[j1];
            snC = srcArr[j2];
            snD = srcArr[j3];
            kvA = kvb4[(size_t)snA * 32 + c];
            kvB = kvb4[(size_t)snB * 32 + c];
            eaA = eh[j0];
            eaB = eh[j1];
        }

        for (int jb = beg; jb < end; jb += 2) {
            int j = jb + h;                        // my edge this iteration
            // issue loads: kv for edge j+4 (2 iters ahead), ea for j+4, src for j+8
            uint4 kvC = kvb4[(size_t)snC * 32 + c];
            int jn = (j + 4 < end) ? j + 4 : last;
            uint4 eaC = eh[jn];
            int j8 = (j + 8 < end) ? j + 8 : last;
            int snE = srcArr[j8];

            // unpack edge attrs (8 fp16)
            float2 e01 = __half22float2(*(const __half2*)&eaA.x);
            float2 e23 = __half22float2(*(const __half2*)&eaA.y);
            float2 e45 = __half22float2(*(const __half2*)&eaA.z);
            float2 e67 = __half22float2(*(const __half2*)&eaA.w);
            float ead[8] = { e01.x, e01.y, e23.x, e23.y, e45.x, e45.y, e67.x, e67.y };

            // e-MLP for my 4 channels
            float ex = be4.x, ey = be4.y, ez = be4.z, ew = be4.w;
#pragma unroll
            for (int d = 0; d < 8; ++d) {
                ex = fmaf(ead[d], we[d].x, ex);
                ey = fmaf(ead[d], we[d].y, ey);
                ez = fmaf(ead[d], we[d].z, ez);
                ew = fmaf(ead[d], we[d].w, ew);
            }

            float2 k01 = __half22float2(*(const __half2*)&kvA.x);
            float2 k23 = __half22float2(*(const __half2*)&kvA.y);
            float2 v01 = __half22float2(*(const __half2*)&kvA.z);
            float2 v23 = __half22float2(*(const __half2*)&kvA.w);

            float p = q4.x * (k01.x + ex) + q4.y * (k01.y + ey)
                    + q4.z * (k23.x + ez) + q4.w * (k23.y + ew);
            // head = 8 lanes: 3-shuffle reduce (halves independent)
            p += __shfl_xor(p, 1);
            p += __shfl_xor(p, 2);
            p += __shfl_xor(p, 4);
            float wg = (j < end) ? __expf(p) : 0.0f;
            s += wg;
            a0 = fmaf(wg, v01.x + ex, a0);
            a1 = fmaf(wg, v01.y + ey, a1);
            a2 = fmaf(wg, v23.x + ez, a2);
            a3 = fmaf(wg, v23.y + ew, a3);

            // rotate pipeline
            kvA = kvB; kvB = kvC;
            eaA = eaB; eaB = eaC;
            snC = snD; snD = snE;
        }

        // combine the two halves (bitwise identical both sides)
        s  += __shfl_xor(s, 32);
        a0 += __shfl_xor(a0, 32);
        a1 += __shfl_xor(a1, 32);
        a2 += __shfl_xor(a2, 32);
        a3 += __shfl_xor(a3, 32);

        float rs = (cnt > 0) ? (1.0f / s) : 0.0f;
        float o0 = a0 * rs, o1 = a1 * rs, o2 = a2 * rs, o3 = a3 * rs;

        uint2 skraw = skh[(size_t)n * 32 + c];
        float2 s01 = __half22float2(*(const __half2*)&skraw.x);
        float2 s23 = __half22float2(*(const __half2*)&skraw.y);
        float4 sk4 = make_float4(s01.x, s01.y, s23.x, s23.y);

        float4 wbo = *(const float4*)&WbL[4 * c];
        float4 wbs = *(const float4*)&WbL[128 + 4 * c];
        float4 wbd = *(const float4*)&WbL[256 + 4 * c];

        float t = o0 * wbo.x + sk4.x * wbs.x + (o0 - sk4.x) * wbd.x
                + o1 * wbo.y + sk4.y * wbs.y + (o1 - sk4.y) * wbd.y
                + o2 * wbo.z + sk4.z * wbs.z + (o2 - sk4.z) * wbd.z
                + o3 * wbo.w + sk4.w * wbs.w + (o3 - sk4.w) * wbd.w;
#pragma unroll
        for (int off = 1; off <= 16; off <<= 1) t += __shfl_xor(t, off);
        float beta = 1.0f / (1.0f + __expf(-t));
        float4 hc4;
        hc4.x = beta * sk4.x + (1.0f - beta) * o0;
        hc4.y = beta * sk4.y + (1.0f - beta) * o1;
        hc4.z = beta * sk4.z + (1.0f - beta) * o2;
        hc4.w = beta * sk4.w + (1.0f - beta) * o3;
        if (h == 0) ((float4*)shc)[w * 32 + c] = hc4;
        // same-wave LDS RAW: no barrier needed
        int cc = lane & 31;
        int half = lane >> 5;
        float acc = 0.0f;
#pragma unroll 8
        for (int i = 0; i < 64; ++i) {
            int ch = half * 64 + i;
            acc += shc[w * 128 + ch] * WlinL[ch * 32 + cc];
        }
        acc += __shfl_xor(acc, 32);
        if (lane < 32) {
            float hv = acc + blinL[lane];
            hv = (hv > 0.0f) ? hv : expm1f(hv);
            if (doWriteH) hlin[n * 32 + lane] = hv;
            atomicAdd(&sbn[lane], hv);
            atomicAdd(&sbn[32 + lane], hv * hv);
            if (doPool) {
                int g = bidx[n];
                int repv = blockIdx.x & (NREPP - 1);
                size_t idx = ((size_t)repv * BB + g) * 32 + lane;
                atomicMax((unsigned*)lstats + GMAX_OFF + idx, fmap_u(hv));
                atomicAdd(lstats + GSUM_OFF + idx, hv);
            }
        }
    }
    __syncthreads();
    if (tid < 64) atomicAdd(&lstats[(blockIdx.x & (NREP - 1)) * 64 + tid], sbn[tid]);
}

// ---------------- rep update from pool partials (BN scale/shift computed inline) ----------------
__global__ void repupd_kernel(const float* __restrict__ lstats,
                              const float* __restrict__ gamma, const float* __restrict__ bnbeta,
                              const int* __restrict__ gstart, float* __restrict__ rep, int assign) {
    int i = blockIdx.x * blockDim.x + threadIdx.x;
    if (i < BB * 32) {
        int g = i >> 5, ch = i & 31;
        // BN finalize for this channel
        float sm = 0.0f, sq = 0.0f;
#pragma unroll
        for (int r = 0; r < NREP; ++r) { sm += lstats[r * 64 + ch]; sq += lstats[r * 64 + 32 + ch]; }
        float mean = sm * (1.0f / NN);
        float var = sq * (1.0f / NN) - mean * mean;
        float scale = gamma[ch] * rsqrtf(var + 1e-5f);
        float shift = bnbeta[ch] - mean * scale;

        int cntg = gstart[g + 1] - gstart[g];
        float vmax = 0.0f, vmean = 0.0f;
        if (cntg > 0) {
            const unsigned* gm = (const unsigned*)lstats + GMAX_OFF;
            const float* gs = lstats + GSUM_OFF;
            unsigned mx = 0u;
            float sum = 0.0f;
#pragma unroll
            for (int r = 0; r < NREPP; ++r) {
                size_t idx = ((size_t)r * BB + g) * 32 + ch;
                unsigned m = gm[idx];
                mx = (m > mx) ? m : mx;
                sum += gs[idx];
            }
            vmax = scale * funmap_u(mx) + shift;
            vmean = scale * (sum / (float)cntg) + shift;
        }
        if (assign) {
            rep[g * 64 + ch] = vmax;
            rep[g * 64 + 32 + ch] = vmean;
        } else {
            rep[g * 64 + ch] += vmax;
            rep[g * 64 + 32 + ch] += vmean;
        }
    }
}

// ---------------- readout MLP: one block per graph ----------------
__device__ __forceinline__ float eluf(float x) { return x > 0.0f ? x : expm1f(x); }

__global__ __launch_bounds__(128) void readout_kernel(
    const float* __restrict__ rep,
    const float* __restrict__ W1, const float* __restrict__ b1,
    const float* __restrict__ W2, const float* __restrict__ b2,
    const float* __restrict__ W3, const float* __restrict__ b3,
    float* __restrict__ out)
{
    __shared__ float sr[64];
    __shared__ float sz1[128];
    __shared__ float sz2[64];
    int g = blockIdx.x;
    int t = threadIdx.x;
    if (t < 64) sr[t] = rep[g * 64 + t];
    __syncthreads();
    float acc = b1[t];
#pragma unroll 8
    for (int i = 0; i < 64; ++i) acc += sr[i] * W1[i * 128 + t];
    sz1[t] = eluf(acc);
    __syncthreads();
    if (t < 64) {
        float a2 = b2[t];
#pragma unroll 8
        for (int i = 0; i < 128; ++i) a2 += sz1[i] * W2[i * 64 + t];
        sz2[t] = eluf(a2);
    }
    __syncthreads();
    if (t < 64) {
        float p = sz2[t] * W3[t];
#pragma unroll
        for (int off = 1; off <= 32; off <<= 1) p += __shfl_xor(p, off);
        if (t == 0) out[g] = p + b3[0];
    }
}

// ---------------- host ----------------

extern "C" void kernel_launch(void* const* d_in, const int* in_sizes, int n_in,
                              void* d_out, int out_size, void* d_ws, size_t ws_size,
                              hipStream_t stream) {
    const float* x      = (const float*)d_in[0];
    const float* eattr  = (const float*)d_in[1];
    const int*   eidx   = (const int*)d_in[2];
    const int*   bidx   = (const int*)d_in[3];
    const float* Wq     = (const float*)d_in[4];
    const float* bq     = (const float*)d_in[5];
    const float* Wk     = (const float*)d_in[6];
    const float* bk     = (const float*)d_in[7];
    const float* Wv     = (const float*)d_in[8];
    const float* bv     = (const float*)d_in[9];
    const float* We     = (const float*)d_in[10];
    const float* be     = (const float*)d_in[11];
    const float* Wskip  = (const float*)d_in[12];
    const float* bskip  = (const float*)d_in[13];
    const float* Wbeta  = (const float*)d_in[14];
    const float* Wlin   = (const float*)d_in[15];
    const float* blin   = (const float*)d_in[16];
    const float* bng    = (const float*)d_in[17];
    const float* bnb    = (const float*)d_in[18];
    const float* W1     = (const float*)d_in[19];
    const float* b1     = (const float*)d_in[20];
    const float* W2     = (const float*)d_in[21];
    const float* b2     = (const float*)d_in[22];
    const float* W3     = (const float*)d_in[23];
    const float* b3     = (const float*)d_in[24];
    float* out = (float*)d_out;

    char* ws = (char*)d_ws;
    size_t off = 0;
    auto alloc = [&](size_t bytes) -> char* {
        char* p = ws + off;
        off = (off + bytes + 255) & ~(size_t)255;
        return p;
    };
    int*     rowp   = (int*)alloc((NN + 1) * 4);
    int*     zeroed = (int*)alloc((2 * NN + 512) * 4);        // deg + cnt2 + hist + bincnt, one memset
    int*     deg    = zeroed;
    int*     cnt2   = zeroed + NN;
    int*     hist   = zeroed + 2 * NN;
    int*     bincnt = zeroed + 2 * NN + 256;
    int*     binstart = (int*)alloc(256 * 4);
    int*     perm   = (int*)alloc(NN * 4);
    int*     csre   = (int*)alloc(EE * 4);
    int*     blks   = (int*)alloc(128 * 4);
    int*     gstart = (int*)alloc((BB + 1) * 4);
    float*   rep    = (float*)alloc(BB * 64 * 4);
    __half2* qH     = (__half2*)alloc((size_t)NN * 64 * 4);   // fp16 q
    __half2* kvB    = (__half2*)alloc((size_t)NN * 128 * 4);  // fp16 kv interleaved
    __half2* skH    = (__half2*)alloc((size_t)NN * 64 * 4);   // fp16 skip
    float*   hlin   = (float*)alloc((size_t)NN * 32 * 4);
    float*   lstats = (float*)alloc(2 * LSTATS_WORDS * 4);    // double-buffered stats
    int*     csrsrc = (int*)alloc(EE * 4);
    uint4*   ecsrh  = (uint4*)alloc((size_t)EE * 16);         // fp16 edge attrs

    const int* srcA = eidx;
    const int* dstA = eidx + EE;

    // --- graph prep (once per call) ---
    (void)hipMemsetAsync(zeroed, 0, (2 * NN + 512) * 4, stream);

    deg_kernel<<<(EE + 255) / 256, 256, 0, stream>>>(dstA, deg);
    scan1_kernel<<<98, 256, 0, stream>>>(deg, rowp, blks, hist);
    scan2_kernel<<<1, 128, 0, stream>>>(blks, 98, bidx, gstart);
    binprep_kernel<<<1, 256, 0, stream>>>(hist, binstart);
    scan3_kernel<<<98, 256, 0, stream>>>(rowp, blks, deg, binstart, bincnt, perm);
    fill_kernel<<<(EE + 255) / 256, 256, 0, stream>>>(dstA, rowp, cnt2, csre);
    sortseg_kernel<<<98, 256, 0, stream>>>(rowp, csre);
    csr_gather_kernel<<<(EE + 255) / 256, 256, 0, stream>>>(csre, srcA, eattr, csrsrc, ecsrh);

    for (int l = 0; l < LL; ++l) {
        float* lcur = lstats + (size_t)(l & 1) * LSTATS_WORDS;
        float* lprev = lstats + (size_t)((l & 1) ^ 1) * LSTATS_WORDS;

        qkvs_kernel<<<782, 256, 0, stream>>>(
            (l == 0) ? x : hlin, (l > 0) ? 1 : 0,
            lprev, lcur,
            bng + (l > 0 ? (l - 1) : 0) * FF, bnb + (l > 0 ? (l - 1) : 0) * FF,
            Wq + l * FF * HCC, bq + l * HCC,
            Wk + l * FF * HCC, bk + l * HCC,
            Wv + l * FF * HCC, bv + l * HCC,
            Wskip + l * FF * HCC, bskip + l * HCC,
            qH, kvB, skH);

        attn_kernel<<<NN / 4, 256, 0, stream>>>(
            (const uint2*)qH, (const uint4*)kvB, (const uint2*)skH,
            ecsrh, csrsrc, rowp, bidx, perm,
            We + l * EDD * HCC, be + l * HCC,
            Wbeta + l * 3 * HCC,
            Wlin + l * HCC * FF, blin + l * FF,
            hlin, lcur,
            (l > 0) ? 1 : 0, (l < LL - 1) ? 1 : 0);

        if (l > 0) {
            repupd_kernel<<<8, 256, 0, stream>>>(lcur, bng + l * FF, bnb + l * FF,
                                                 gstart, rep, (l == 1) ? 1 : 0);
        }
    }

    readout_kernel<<<64, 128, 0, stream>>>(rep, W1, b1, W2, b2, W3, b3, out);
}

// Round 18
// 532.299 us; speedup vs baseline: 1.1612x; 1.1612x over previous
//
#include <hip/hip_runtime.h>
#include <hip/hip_bf16.h>
#include <hip/hip_fp16.h>
#include <math.h>

#define NN 25000
#define EE 400000
#define BB 64
#define FF 32
#define EDD 8
#define HH 4
#define CC 32
#define HCC 128
#define LL 4
#define LINN 128

#define RSQRT_C 0.17677669529663687f  // 1/sqrt(32)
#define NREP 16                        // bnpart replicas
#define NREPP 8                        // pool replicas
// lstats region layout: bnpart[NREP*64] | gmax[NREPP*BB*32] (uint) | gsum[NREPP*BB*32]
#define GMAX_OFF (NREP * 64)
#define GSUM_OFF (NREP * 64 + NREPP * BB * 32)
#define LSTATS_WORDS (NREP * 64 + 2 * NREPP * BB * 32)

// ---------------- CSR build ----------------

__global__ void deg_kernel(const int* __restrict__ dst, int* __restrict__ deg) {
    int i = blockIdx.x * blockDim.x + threadIdx.x;
    if (i < EE) atomicAdd(&deg[dst[i]], 1);
}

// inclusive scan within 256-blocks; writes to rowp[i+1], block totals to blks
__global__ void scan1_kernel(const int* __restrict__ deg, int* __restrict__ rowp, int* __restrict__ blks) {
    __shared__ int s[256];
    int i = blockIdx.x * 256 + threadIdx.x;
    int v = (i < NN) ? deg[i] : 0;
    s[threadIdx.x] = v;
    __syncthreads();
    for (int off = 1; off < 256; off <<= 1) {
        int t = (threadIdx.x >= off) ? s[threadIdx.x - off] : 0;
        __syncthreads();
        s[threadIdx.x] += t;
        __syncthreads();
    }
    if (i < NN) rowp[i + 1] = s[threadIdx.x];
    if (threadIdx.x == 255) blks[blockIdx.x] = s[255];
    if (i == 0) rowp[0] = 0;
}

// parallel exclusive scan of block totals (nb <= 128) + gstart binary searches
__global__ void scan2_kernel(int* __restrict__ blks, int nb,
                             const int* __restrict__ bidx, int* __restrict__ gstart) {
    __shared__ int s[128];
    int t = threadIdx.x;
    int v = (t < nb) ? blks[t] : 0;
    s[t] = v;
    __syncthreads();
    for (int off = 1; off < 128; off <<= 1) {
        int u = (t >= off) ? s[t - off] : 0;
        __syncthreads();
        s[t] += u;
        __syncthreads();
    }
    if (t < nb) blks[t] = s[t] - v;  // exclusive
    if (t <= BB) {
        int lo = 0, hi = NN;
        while (lo < hi) { int mid = (lo + hi) >> 1; if (bidx[mid] < t) lo = mid + 1; else hi = mid; }
        gstart[t] = lo;
    }
}

__global__ void scan3_kernel(int* __restrict__ rowp, const int* __restrict__ blks) {
    int i = blockIdx.x * 256 + threadIdx.x;
    if (i < NN) rowp[i + 1] += blks[blockIdx.x];
}

__global__ void fill_kernel(const int* __restrict__ dst, const int* __restrict__ rowp,
                            int* __restrict__ cnt2, int* __restrict__ eid) {
    int i = blockIdx.x * blockDim.x + threadIdx.x;
    if (i < EE) {
        int d = dst[i];
        int pos = rowp[d] + atomicAdd(&cnt2[d], 1);
        eid[pos] = i;
    }
}

// deterministic order: insertion-sort each node's edge list by edge id (scratch buffer)
__global__ void sortseg_kernel(const int* __restrict__ rowp, int* __restrict__ eid) {
    int n = blockIdx.x * 256 + threadIdx.x;
    if (n >= NN) return;
    int b = rowp[n], e = rowp[n + 1];
    int d = e - b;
    if (d <= 1) return;
    if (d <= 64) {
        int buf[64];
        for (int i = 0; i < d; ++i) buf[i] = eid[b + i];
        for (int i = 1; i < d; ++i) {
            int key = buf[i];
            int j = i - 1;
            while (j >= 0 && buf[j] > key) { buf[j + 1] = buf[j]; --j; }
            buf[j + 1] = key;
        }
        for (int i = 0; i < d; ++i) eid[b + i] = buf[i];
    } else {
        for (int i = b + 1; i < e; ++i) {
            int key = eid[i];
            int j = i - 1;
            while (j >= b && eid[j] > key) { eid[j + 1] = eid[j]; --j; }
            eid[j + 1] = key;
        }
    }
}

// gather src + edge-attr (fp16-packed) into CSR order (once per call, reused 4 layers)
__global__ void csr_gather_kernel(const int* __restrict__ csre, const int* __restrict__ srcA,
                                  const float* __restrict__ eattr,
                                  int* __restrict__ csrsrc, uint4* __restrict__ eh) {
    int j = blockIdx.x * blockDim.x + threadIdx.x;
    if (j < EE) {
        int e = csre[j];
        csrsrc[j] = srcA[e];
        const float4* s = (const float4*)(eattr + (size_t)e * 8);
        float4 s0 = s[0], s1 = s[1];
        __half2 h0 = __float22half2_rn(make_float2(s0.x, s0.y));
        __half2 h1 = __float22half2_rn(make_float2(s0.z, s0.w));
        __half2 h2 = __float22half2_rn(make_float2(s1.x, s1.y));
        __half2 h3 = __float22half2_rn(make_float2(s1.z, s1.w));
        uint4 o;
        o.x = *(unsigned*)&h0; o.y = *(unsigned*)&h1;
        o.z = *(unsigned*)&h2; o.w = *(unsigned*)&h3;
        eh[j] = o;
    }
}

// ---------------- per-layer: q,k,v,skip projections (+inline BN of input) ----------------
// wave 0: q, wave 1: k, wave 2: v, wave 3: skip. lane l owns channels 2l, 2l+1.
// BN scale/shift computed inline from lstats_prev (bnpart of previous layer).
// block 0 zeroes the CURRENT layer's stats region (different buffer: no race).
__global__ __launch_bounds__(256) void qkvs_kernel(
    const float* __restrict__ hin, int applyBN,
    const float* __restrict__ lstats_prev, float* __restrict__ lstats_cur,
    const float* __restrict__ gamma, const float* __restrict__ bnbeta,
    const float* __restrict__ Wq, const float* __restrict__ bq,
    const float* __restrict__ Wk, const float* __restrict__ bk,
    const float* __restrict__ Wv, const float* __restrict__ bv,
    const float* __restrict__ Ws, const float* __restrict__ bs,
    __half2* __restrict__ qo, __half2* __restrict__ kvo,
    __half2* __restrict__ so)
{
    if (blockIdx.x == 0) {
        for (int i = threadIdx.x; i < LSTATS_WORDS; i += 256) lstats_cur[i] = 0.0f;
    }
    __shared__ float xs[32][32];
    __shared__ float sbns[64];
    if (threadIdx.x < 32) {
        float scale = 1.0f, shift = 0.0f;
        if (applyBN) {
            float sm = 0.0f, sq = 0.0f;
#pragma unroll
            for (int r = 0; r < NREP; ++r) {
                sm += lstats_prev[r * 64 + threadIdx.x];
                sq += lstats_prev[r * 64 + 32 + threadIdx.x];
            }
            float mean = sm * (1.0f / NN);
            float var = sq * (1.0f / NN) - mean * mean;
            scale = gamma[threadIdx.x] * rsqrtf(var + 1e-5f);
            shift = bnbeta[threadIdx.x] - mean * scale;
        }
        sbns[threadIdx.x] = scale;
        sbns[32 + threadIdx.x] = shift;
    }
    int lane = threadIdx.x & 63;
    int sel = threadIdx.x >> 6;
    const float* W = (sel == 0) ? Wq : (sel == 1) ? Wk : (sel == 2) ? Wv : Ws;
    const float* bias = (sel == 0) ? bq : (sel == 1) ? bk : (sel == 2) ? bv : bs;
    float w0[32], w1[32];
#pragma unroll
    for (int f = 0; f < 32; ++f) {
        float2 t = *(const float2*)&W[f * 128 + 2 * lane];
        w0[f] = t.x; w1[f] = t.y;
    }
    float2 bvv = *(const float2*)&bias[2 * lane];

    int c = lane >> 1;
    int pr = lane & 1;
    int h2k = c * 4 + pr;          // __half2 slot for k within kv row
    int h2v = c * 4 + 2 + pr;      // __half2 slot for v within kv row

    for (int chunk = blockIdx.x * 32; chunk < NN; chunk += gridDim.x * 32) {
        __syncthreads();
        for (int i = threadIdx.x; i < 1024; i += 256) {
            int nn = chunk + (i >> 5);
            int ch = i & 31;
            float v = (nn < NN) ? hin[nn * 32 + ch] : 0.0f;
            xs[i >> 5][ch] = v * sbns[ch] + sbns[32 + ch];
        }
        __syncthreads();
        int nmax = NN - chunk; if (nmax > 32) nmax = 32;
        for (int nl = 0; nl < nmax; ++nl) {
            float a0 = bvv.x, a1 = bvv.y;
#pragma unroll
            for (int f4 = 0; f4 < 8; ++f4) {
                float4 xv = *(const float4*)&xs[nl][f4 * 4];
                a0 = fmaf(xv.x, w0[f4 * 4],     a0);
                a1 = fmaf(xv.x, w1[f4 * 4],     a1);
                a0 = fmaf(xv.y, w0[f4 * 4 + 1], a0);
                a1 = fmaf(xv.y, w1[f4 * 4 + 1], a1);
                a0 = fmaf(xv.z, w0[f4 * 4 + 2], a0);
                a1 = fmaf(xv.z, w1[f4 * 4 + 2], a1);
                a0 = fmaf(xv.w, w0[f4 * 4 + 3], a0);
                a1 = fmaf(xv.w, w1[f4 * 4 + 3], a1);
            }
            size_t node = (size_t)(chunk + nl);
            __half2 hv = __float22half2_rn(make_float2(a0, a1));
            if (sel == 0)      qo[node * 64 + lane] = hv;
            else if (sel == 1) kvo[node * 128 + h2k] = hv;
            else if (sel == 2) kvo[node * 128 + h2v] = hv;
            else               so[node * 64 + lane] = hv;
        }
    }
}

__device__ __forceinline__ unsigned fmap_u(float x) {
    unsigned u = __float_as_uint(x);
    return (u & 0x80000000u) ? ~u : (u | 0x80000000u);
}
__device__ __forceinline__ float funmap_u(unsigned u) {
    unsigned b = (u & 0x80000000u) ? (u & 0x7fffffffu) : ~u;
    return __uint_as_float(b);
}

// ---------------- fused attention + beta gate + Wlin + ELU + BN partials + pool partials ----------------
// 4 waves/block, 1 dst node per wave. Lane c=lane&31 owns channels 4c..4c+3;
// half h=lane>>5 processes edge j = jb + h (2 edges per iteration).
// NOTE: no min-waves launch bound — r13 showed forcing 8 waves/EU spills (VGPR 32, 8x traffic).
__global__ __launch_bounds__(256) void attn_kernel(
    const uint2* __restrict__ qh, const uint4* __restrict__ kvb4,
    const uint2* __restrict__ skh,
    const uint4* __restrict__ eh,         // fp16 edge attrs, 16B/edge
    const int* __restrict__ srcArr,       // csrsrc[j]
    const int* __restrict__ rowp,
    const int* __restrict__ bidx,
    const float* __restrict__ WeL, const float* __restrict__ beL,
    const float* __restrict__ WbL,
    const float* __restrict__ WlinL, const float* __restrict__ blinL,
    float* __restrict__ hlin, float* __restrict__ lstats,
    int doPool, int doWriteH)
{
    __shared__ __align__(16) float shc[4 * 128];
    __shared__ float sbn[64];

    int tid = threadIdx.x;
    if (tid < 64) sbn[tid] = 0.0f;
    __syncthreads();

    int w = tid >> 6;
    int lane = tid & 63;
    int n = blockIdx.x * 4 + w;

    if (n < NN) {
        int c = lane & 31;
        int h = lane >> 5;

        // per-lane We rows for channels 4c..4c+3
        float4 we[8];
#pragma unroll
        for (int d = 0; d < 8; ++d) we[d] = *(const float4*)&WeL[d * 128 + 4 * c];
        float4 be4 = *(const float4*)&beL[4 * c];

        uint2 qraw = qh[(size_t)n * 32 + c];
        float2 q01 = __half22float2(*(const __half2*)&qraw.x);
        float2 q23 = __half22float2(*(const __half2*)&qraw.y);
        float4 q4 = make_float4(q01.x * RSQRT_C, q01.y * RSQRT_C,
                                q23.x * RSQRT_C, q23.y * RSQRT_C);

        int beg = rowp[n], end = rowp[n + 1];
        int cnt = end - beg;
        int last = end - 1;

        float s = 0.0f, a0 = 0.0f, a1 = 0.0f, a2 = 0.0f, a3 = 0.0f;

        // pipeline state (per half): edges j, j+2 in regs; src for j+4, j+6
        uint4 kvA = make_uint4(0u, 0u, 0u, 0u), kvB = kvA;
        uint4 eaA = kvA, eaB = kvA;
        int snC = 0, snD = 0;

        if (cnt > 0) {
            int j0 = beg + h;     j0 = (j0 < end) ? j0 : last;
            int j1 = beg + 2 + h; j1 = (j1 < end) ? j1 : last;
            int j2 = beg + 4 + h; j2 = (j2 < end) ? j2 : last;
            int j3 = beg + 6 + h; j3 = (j3 < end) ? j3 : last;
            int snA = srcArr[j0];
            int snB = srcArr[j1];
            snC = srcArr[j2];
            snD = srcArr[j3];
            kvA = kvb4[(size_t)snA * 32 + c];
            kvB = kvb4[(size_t)snB * 32 + c];
            eaA = eh[j0];
            eaB = eh[j1];
        }

        for (int jb = beg; jb < end; jb += 2) {
            int j = jb + h;                        // my edge this iteration
            // issue loads: kv for edge j+4 (2 iters ahead), ea for j+4, src for j+8
            uint4 kvC = kvb4[(size_t)snC * 32 + c];
            int jn = (j + 4 < end) ? j + 4 : last;
            uint4 eaC = eh[jn];
            int j8 = (j + 8 < end) ? j + 8 : last;
            int snE = srcArr[j8];

            // unpack edge attrs (8 fp16)
            float2 e01 = __half22float2(*(const __half2*)&eaA.x);
            float2 e23 = __half22float2(*(const __half2*)&eaA.y);
            float2 e45 = __half22float2(*(const __half2*)&eaA.z);
            float2 e67 = __half22float2(*(const __half2*)&eaA.w);
            float ead[8] = { e01.x, e01.y, e23.x, e23.y, e45.x, e45.y, e67.x, e67.y };

            // e-MLP for my 4 channels
            float ex = be4.x, ey = be4.y, ez = be4.z, ew = be4.w;
#pragma unroll
            for (int d = 0; d < 8; ++d) {
                ex = fmaf(ead[d], we[d].x, ex);
                ey = fmaf(ead[d], we[d].y, ey);
                ez = fmaf(ead[d], we[d].z, ez);
                ew = fmaf(ead[d], we[d].w, ew);
            }

            float2 k01 = __half22float2(*(const __half2*)&kvA.x);
            float2 k23 = __half22float2(*(const __half2*)&kvA.y);
            float2 v01 = __half22float2(*(const __half2*)&kvA.z);
            float2 v23 = __half22float2(*(const __half2*)&kvA.w);

            float p = q4.x * (k01.x + ex) + q4.y * (k01.y + ey)
                    + q4.z * (k23.x + ez) + q4.w * (k23.y + ew);
            // head = 8 lanes: 3-shuffle reduce (halves independent)
            p += __shfl_xor(p, 1);
            p += __shfl_xor(p, 2);
            p += __shfl_xor(p, 4);
            float wg = (j < end) ? __expf(p) : 0.0f;
            s += wg;
            a0 = fmaf(wg, v01.x + ex, a0);
            a1 = fmaf(wg, v01.y + ey, a1);
            a2 = fmaf(wg, v23.x + ez, a2);
            a3 = fmaf(wg, v23.y + ew, a3);

            // rotate pipeline
            kvA = kvB; kvB = kvC;
            eaA = eaB; eaB = eaC;
            snC = snD; snD = snE;
        }

        // combine the two halves (bitwise identical both sides)
        s  += __shfl_xor(s, 32);
        a0 += __shfl_xor(a0, 32);
        a1 += __shfl_xor(a1, 32);
        a2 += __shfl_xor(a2, 32);
        a3 += __shfl_xor(a3, 32);

        float rs = (cnt > 0) ? (1.0f / s) : 0.0f;
        float o0 = a0 * rs, o1 = a1 * rs, o2 = a2 * rs, o3 = a3 * rs;

        uint2 skraw = skh[(size_t)n * 32 + c];
        float2 s01 = __half22float2(*(const __half2*)&skraw.x);
        float2 s23 = __half22float2(*(const __half2*)&skraw.y);
        float4 sk4 = make_float4(s01.x, s01.y, s23.x, s23.y);

        float4 wbo = *(const float4*)&WbL[4 * c];
        float4 wbs = *(const float4*)&WbL[128 + 4 * c];
        float4 wbd = *(const float4*)&WbL[256 + 4 * c];

        float t = o0 * wbo.x + sk4.x * wbs.x + (o0 - sk4.x) * wbd.x
                + o1 * wbo.y + sk4.y * wbs.y + (o1 - sk4.y) * wbd.y
                + o2 * wbo.z + sk4.z * wbs.z + (o2 - sk4.z) * wbd.z
                + o3 * wbo.w + sk4.w * wbs.w + (o3 - sk4.w) * wbd.w;
#pragma unroll
        for (int off = 1; off <= 16; off <<= 1) t += __shfl_xor(t, off);
        float beta = 1.0f / (1.0f + __expf(-t));
        float4 hc4;
        hc4.x = beta * sk4.x + (1.0f - beta) * o0;
        hc4.y = beta * sk4.y + (1.0f - beta) * o1;
        hc4.z = beta * sk4.z + (1.0f - beta) * o2;
        hc4.w = beta * sk4.w + (1.0f - beta) * o3;
        if (h == 0) ((float4*)shc)[w * 32 + c] = hc4;
        // same-wave LDS RAW: no barrier needed
        int cc = lane & 31;
        int half = lane >> 5;
        float acc = 0.0f;
#pragma unroll 8
        for (int i = 0; i < 64; ++i) {
            int ch = half * 64 + i;
            acc += shc[w * 128 + ch] * WlinL[ch * 32 + cc];
        }
        acc += __shfl_xor(acc, 32);
        if (lane < 32) {
            float hv = acc + blinL[lane];
            hv = (hv > 0.0f) ? hv : expm1f(hv);
            if (doWriteH) hlin[n * 32 + lane] = hv;
            atomicAdd(&sbn[lane], hv);
            atomicAdd(&sbn[32 + lane], hv * hv);
            if (doPool) {
                int g = bidx[n];
                int repv = blockIdx.x & (NREPP - 1);
                size_t idx = ((size_t)repv * BB + g) * 32 + lane;
                atomicMax((unsigned*)lstats + GMAX_OFF + idx, fmap_u(hv));
                atomicAdd(lstats + GSUM_OFF + idx, hv);
            }
        }
    }
    __syncthreads();
    if (tid < 64) atomicAdd(&lstats[(blockIdx.x & (NREP - 1)) * 64 + tid], sbn[tid]);
}

// ---------------- rep update from pool partials (BN scale/shift computed inline) ----------------
__global__ void repupd_kernel(const float* __restrict__ lstats,
                              const float* __restrict__ gamma, const float* __restrict__ bnbeta,
                              const int* __restrict__ gstart, float* __restrict__ rep, int assign) {
    int i = blockIdx.x * blockDim.x + threadIdx.x;
    if (i < BB * 32) {
        int g = i >> 5, ch = i & 31;
        // BN finalize for this channel
        float sm = 0.0f, sq = 0.0f;
#pragma unroll
        for (int r = 0; r < NREP; ++r) { sm += lstats[r * 64 + ch]; sq += lstats[r * 64 + 32 + ch]; }
        float mean = sm * (1.0f / NN);
        float var = sq * (1.0f / NN) - mean * mean;
        float scale = gamma[ch] * rsqrtf(var + 1e-5f);
        float shift = bnbeta[ch] - mean * scale;

        int cntg = gstart[g + 1] - gstart[g];
        float vmax = 0.0f, vmean = 0.0f;
        if (cntg > 0) {
            const unsigned* gm = (const unsigned*)lstats + GMAX_OFF;
            const float* gs = lstats + GSUM_OFF;
            unsigned mx = 0u;
            float sum = 0.0f;
#pragma unroll
            for (int r = 0; r < NREPP; ++r) {
                size_t idx = ((size_t)r * BB + g) * 32 + ch;
                unsigned m = gm[idx];
                mx = (m > mx) ? m : mx;
                sum += gs[idx];
            }
            vmax = scale * funmap_u(mx) + shift;
            vmean = scale * (sum / (float)cntg) + shift;
        }
        if (assign) {
            rep[g * 64 + ch] = vmax;
            rep[g * 64 + 32 + ch] = vmean;
        } else {
            rep[g * 64 + ch] += vmax;
            rep[g * 64 + 32 + ch] += vmean;
        }
    }
}

// ---------------- readout MLP: one block per graph ----------------
__device__ __forceinline__ float eluf(float x) { return x > 0.0f ? x : expm1f(x); }

__global__ __launch_bounds__(128) void readout_kernel(
    const float* __restrict__ rep,
    const float* __restrict__ W1, const float* __restrict__ b1,
    const float* __restrict__ W2, const float* __restrict__ b2,
    const float* __restrict__ W3, const float* __restrict__ b3,
    float* __restrict__ out)
{
    __shared__ float sr[64];
    __shared__ float sz1[128];
    __shared__ float sz2[64];
    int g = blockIdx.x;
    int t = threadIdx.x;
    if (t < 64) sr[t] = rep[g * 64 + t];
    __syncthreads();
    float acc = b1[t];
#pragma unroll 8
    for (int i = 0; i < 64; ++i) acc += sr[i] * W1[i * 128 + t];
    sz1[t] = eluf(acc);
    __syncthreads();
    if (t < 64) {
        float a2 = b2[t];
#pragma unroll 8
        for (int i = 0; i < 128; ++i) a2 += sz1[i] * W2[i * 64 + t];
        sz2[t] = eluf(a2);
    }
    __syncthreads();
    if (t < 64) {
        float p = sz2[t] * W3[t];
#pragma unroll
        for (int off = 1; off <= 32; off <<= 1) p += __shfl_xor(p, off);
        if (t == 0) out[g] = p + b3[0];
    }
}

// ---------------- host ----------------

extern "C" void kernel_launch(void* const* d_in, const int* in_sizes, int n_in,
                              void* d_out, int out_size, void* d_ws, size_t ws_size,
                              hipStream_t stream) {
    const float* x      = (const float*)d_in[0];
    const float* eattr  = (const float*)d_in[1];
    const int*   eidx   = (const int*)d_in[2];
    const int*   bidx   = (const int*)d_in[3];
    const float* Wq     = (const float*)d_in[4];
    const float* bq     = (const float*)d_in[5];
    const float* Wk     = (const float*)d_in[6];
    const float* bk     = (const float*)d_in[7];
    const float* Wv     = (const float*)d_in[8];
    const float* bv     = (const float*)d_in[9];
    const float* We     = (const float*)d_in[10];
    const float* be     = (const float*)d_in[11];
    const float* Wskip  = (const float*)d_in[12];
    const float* bskip  = (const float*)d_in[13];
    const float* Wbeta  = (const float*)d_in[14];
    const float* Wlin   = (const float*)d_in[15];
    const float* blin   = (const float*)d_in[16];
    const float* bng    = (const float*)d_in[17];
    const float* bnb    = (const float*)d_in[18];
    const float* W1     = (const float*)d_in[19];
    const float* b1     = (const float*)d_in[20];
    const float* W2     = (const float*)d_in[21];
    const float* b2     = (const float*)d_in[22];
    const float* W3     = (const float*)d_in[23];
    const float* b3     = (const float*)d_in[24];
    float* out = (float*)d_out;

    char* ws = (char*)d_ws;
    size_t off = 0;
    auto alloc = [&](size_t bytes) -> char* {
        char* p = ws + off;
        off = (off + bytes + 255) & ~(size_t)255;
        return p;
    };
    int*     rowp   = (int*)alloc((NN + 1) * 4);
    int*     degcnt = (int*)alloc(2 * NN * 4);              // deg + cnt2, one memset
    int*     deg    = degcnt;
    int*     cnt2   = degcnt + NN;
    int*     csre   = (int*)alloc(EE * 4);
    int*     blks   = (int*)alloc(128 * 4);
    int*     gstart = (int*)alloc((BB + 1) * 4);
    float*   rep    = (float*)alloc(BB * 64 * 4);
    __half2* qH     = (__half2*)alloc((size_t)NN * 64 * 4);   // fp16 q
    __half2* kvB    = (__half2*)alloc((size_t)NN * 128 * 4);  // fp16 kv interleaved
    __half2* skH    = (__half2*)alloc((size_t)NN * 64 * 4);   // fp16 skip
    float*   hlin   = (float*)alloc((size_t)NN * 32 * 4);
    float*   lstats = (float*)alloc(2 * LSTATS_WORDS * 4);    // double-buffered stats
    int*     csrsrc = (int*)alloc(EE * 4);
    uint4*   ecsrh  = (uint4*)alloc((size_t)EE * 16);         // fp16 edge attrs

    const int* srcA = eidx;
    const int* dstA = eidx + EE;

    // --- graph prep (once per call) ---
    (void)hipMemsetAsync(degcnt, 0, 2 * NN * 4, stream);

    deg_kernel<<<(EE + 255) / 256, 256, 0, stream>>>(dstA, deg);
    scan1_kernel<<<98, 256, 0, stream>>>(deg, rowp, blks);
    scan2_kernel<<<1, 128, 0, stream>>>(blks, 98, bidx, gstart);
    scan3_kernel<<<98, 256, 0, stream>>>(rowp, blks);
    fill_kernel<<<(EE + 255) / 256, 256, 0, stream>>>(dstA, rowp, cnt2, csre);
    sortseg_kernel<<<98, 256, 0, stream>>>(rowp, csre);
    csr_gather_kernel<<<(EE + 255) / 256, 256, 0, stream>>>(csre, srcA, eattr, csrsrc, ecsrh);

    for (int l = 0; l < LL; ++l) {
        float* lcur = lstats + (size_t)(l & 1) * LSTATS_WORDS;
        float* lprev = lstats + (size_t)((l & 1) ^ 1) * LSTATS_WORDS;

        qkvs_kernel<<<782, 256, 0, stream>>>(
            (l == 0) ? x : hlin, (l > 0) ? 1 : 0,
            lprev, lcur,
            bng + (l > 0 ? (l - 1) : 0) * FF, bnb + (l > 0 ? (l - 1) : 0) * FF,
            Wq + l * FF * HCC, bq + l * HCC,
            Wk + l * FF * HCC, bk + l * HCC,
            Wv + l * FF * HCC, bv + l * HCC,
            Wskip + l * FF * HCC, bskip + l * HCC,
            qH, kvB, skH);

        attn_kernel<<<(NN + 3) / 4, 256, 0, stream>>>(
            (const uint2*)qH, (const uint4*)kvB, (const uint2*)skH,
            ecsrh, csrsrc, rowp, bidx,
            We + l * EDD * HCC, be + l * HCC,
            Wbeta + l * 3 * HCC,
            Wlin + l * HCC * FF, blin + l * FF,
            hlin, lcur,
            (l > 0) ? 1 : 0, (l < LL - 1) ? 1 : 0);

        if (l > 0) {
            repupd_kernel<<<8, 256, 0, stream>>>(lcur, bng + l * FF, bnb + l * FF,
                                                 gstart, rep, (l == 1) ? 1 : 0);
        }
    }

    readout_kernel<<<64, 128, 0, stream>>>(rep, W1, b1, W2, b2, W3, b3, out);
}